// Round 1
// 164.223 us; speedup vs baseline: 1.1909x; 1.1909x over previous
//
#include <hip/hip_runtime.h>
#include <hip/hip_bf16.h>

typedef unsigned int u32;
typedef unsigned short u16;
typedef unsigned long long u64;
typedef __attribute__((ext_vector_type(8))) short short8;
typedef __attribute__((ext_vector_type(4))) float f32x4;

#define BATCH 4
#define SEQ   4096
#define DIM   768
#define HD    64
#define NROW  (BATCH*SEQ)   // 16384
#define LOG2E 1.44269504088896f
#define SSCALE (0.125f * LOG2E)
#define CSHIFT (-32.0f)      // fixed exp2-domain shift (softmax shift-invariant)
#define NEGBIG (-1.0e30f)
#define VSTRIDE 4224         // vT row stride in u16 (breaks L2 channel camping)
#define PSLOTB 4224          // partial slot: 4096 B bf16 O[32][64] + 128 B f32 l[32]

__device__ __forceinline__ float ex2(float x) { return __builtin_amdgcn_exp2f(x); }
__device__ __forceinline__ float bfbits2f(u16 u) {
    return __uint_as_float(((u32)u) << 16);
}
__device__ __forceinline__ u16 f2bf(float f) {
    return (u16)((__float_as_uint(f) + 0x8000u) >> 16);
}
__device__ __forceinline__ u32 pkbf(float a, float b) { // lo16=bf(a), hi16=bf(b)
    u32 xa = __float_as_uint(a) + 0x8000u;
    u32 xb = __float_as_uint(b) + 0x8000u;
    return __builtin_amdgcn_perm(xb, xa, 0x07060302);
}
// Deterministic per-wave dtype sniff (same answer in every wave/block).
__device__ __forceinline__ int sniff_bf16(const u32* x) {
    u32 w = x[threadIdx.x & 63];
    u32 lo = w & 0xffffu;
    u32 e  = (lo >> 7) & 0xffu;
    bool ok = (lo == 0u) || (e >= 96u && e <= 134u);
    u64 bal = __ballot(ok);
    return (__popcll(bal) >= 48) ? 1 : 0;
}

// ---------------- QKV projection: LDS-tiled GEMM (m97 shape) ----------------
// Blocks 0..255: block tile = 64 rows x 192 cols, K staged 64-wide in LDS
// (X 8 KB + W 24 KB, chunk^(row&7) swizzle), register prefetch of next tile.
// 8 waves = 4 row-strips x 2 col-halves: 12 MFMA + 14 ds_read_b128 per K-step.
// Blocks 256..257: bit-pack padding mask via ballot.
__global__ __launch_bounds__(512, 4) void qkv_kernel(
    const void* __restrict__ x,
    const void* __restrict__ wq, const void* __restrict__ wk,
    const void* __restrict__ wv, const int* __restrict__ mask,
    u16* __restrict__ qws, u16* __restrict__ kws, u16* __restrict__ vTws,
    u32* __restrict__ mb)
{
    const int t = threadIdx.x;
    const int l = t & 63;
    const int w = t >> 6;

    if (blockIdx.x >= 256) {            // ---- mask bit-pack ----
        const int base = (blockIdx.x - 256) * 8192 + w * 1024;
#pragma unroll
        for (int it = 0; it < 16; ++it) {
            const int idx = base + it * 64 + l;
            u64 bal = __ballot(mask[idx] != 0);
            if (l == 0)       mb[idx >> 5] = (u32)bal;
            else if (l == 32) mb[idx >> 5] = (u32)(bal >> 32);
        }
        return;
    }

    const int flag = sniff_bf16((const u32*)x);
    __shared__ __align__(16) u16 Xl[64 * 64];    // 8 KB,  slot r*64 + cc*8
    __shared__ __align__(16) u16 Wl[192 * 64];   // 24 KB, slot n*64 + cc*8
    __shared__ u16 Vt[64][66];                   // 8.4 KB transpose staging

    const int li = l & 15;
    const int g  = l >> 4;
    const int g4 = g * 4;
    const int strip = w & 3;            // 16-row strip
    const int nhalf = w >> 2;           // 96-col half
    const int m0 = blockIdx.x * 64;
    const int b  = m0 >> 12;

    auto ldbf = [&](const void* bp, long off) -> short8 {
        if (flag) return *reinterpret_cast<const short8*>((const u16*)bp + off);
        const float* p = (const float*)bp + off;
        float4 a = *reinterpret_cast<const float4*>(p);
        float4 c = *reinterpret_cast<const float4*>(p + 4);
        union { u32 u[4]; short8 s; } un;
        un.u[0] = pkbf(a.x, a.y); un.u[1] = pkbf(a.z, a.w);
        un.u[2] = pkbf(c.x, c.y); un.u[3] = pkbf(c.z, c.w);
        return un.s;
    };

    // ---- staging source mapping (kc-invariant parts) ----
    const int xr = t >> 3, xcc = t & 7, xc = xcc ^ (xr & 7);
    const long xsoff = (long)(m0 + xr) * DIM + xc * 8;
    const void* wsel[3]; long wsoff[3]; int wdst[3];
#pragma unroll
    for (int j = 0; j < 3; ++j) {
        const int idx = j * 512 + t;
        const int r = idx >> 3, cc = idx & 7, c = cc ^ (r & 7);
        wsel[j] = (r < 64) ? wq : (r < 128) ? wk : wv;
        wsoff[j] = (long)(r & 63) * DIM + c * 8;
        wdst[j]  = idx * 8;             // u16 offset into Wl
    }

    // ---- fragment read offsets (kc-invariant, u16 units) ----
    const int am = strip * 16 + li;
    const int a0off = am * 64 + ((g       ^ (am & 7)) * 8);
    const int a1off = am * 64 + (((g | 4) ^ (am & 7)) * 8);
    int boff[12];
#pragma unroll
    for (int ns = 0; ns < 6; ++ns) {
        const int n = nhalf * 96 + ns * 16 + li;
        boff[2*ns]   = n * 64 + ((g       ^ (n & 7)) * 8);
        boff[2*ns+1] = n * 64 + (((g | 4) ^ (n & 7)) * 8);
    }

    f32x4 acc[6];
#pragma unroll
    for (int i = 0; i < 6; ++i) acc[i] = (f32x4){0.f, 0.f, 0.f, 0.f};

    short8 xs  = ldbf(x, xsoff);
    short8 ws0 = ldbf(wsel[0], wsoff[0]);
    short8 ws1 = ldbf(wsel[1], wsoff[1]);
    short8 ws2 = ldbf(wsel[2], wsoff[2]);

    for (int kc = 0; kc < 12; ++kc) {
        __syncthreads();                 // previous K-step's LDS reads done
        *reinterpret_cast<short8*>(&Xl[t * 8])    = xs;
        *reinterpret_cast<short8*>(&Wl[wdst[0]])  = ws0;
        *reinterpret_cast<short8*>(&Wl[wdst[1]])  = ws1;
        *reinterpret_cast<short8*>(&Wl[wdst[2]])  = ws2;
        if (kc < 11) {                   // prefetch next staging tile
            const long o = (long)(kc + 1) * 64;
            xs  = ldbf(x, xsoff + o);
            ws0 = ldbf(wsel[0], wsoff[0] + o);
            ws1 = ldbf(wsel[1], wsoff[1] + o);
            ws2 = ldbf(wsel[2], wsoff[2] + o);
        }
        __syncthreads();                 // staging visible
        short8 af0 = *reinterpret_cast<const short8*>(&Xl[a0off]);
        short8 af1 = *reinterpret_cast<const short8*>(&Xl[a1off]);
#pragma unroll
        for (int ns = 0; ns < 6; ++ns) {
            short8 b0 = *reinterpret_cast<const short8*>(&Wl[boff[2*ns]]);
            short8 b1 = *reinterpret_cast<const short8*>(&Wl[boff[2*ns+1]]);
            acc[ns] = __builtin_amdgcn_mfma_f32_16x16x32_bf16(af0, b0, acc[ns], 0, 0, 0);
            acc[ns] = __builtin_amdgcn_mfma_f32_16x16x32_bf16(af1, b1, acc[ns], 0, 0, 0);
        }
    }

    // epilogue: C row = m0 + strip*16 + g4 + r, col n = nhalf*96 + ns*16 + li
#pragma unroll
    for (int ns = 0; ns < 6; ++ns) {
        const int n = nhalf * 96 + ns * 16 + li;
#pragma unroll
        for (int r = 0; r < 4; ++r) {
            const int rowl = strip * 16 + g4 + r;
            u16 bv = f2bf(acc[ns][r]);
            if (n < 64)        qws[(long)(m0 + rowl) * HD + n]        = bv;
            else if (n < 128)  kws[(long)(m0 + rowl) * HD + (n - 64)] = bv;
            else               Vt[rowl][n - 128]                      = bv;
        }
    }
    __syncthreads();
    // transpose v out: vT[(b*64+d)][ (m0&4095) + mg*8 .. +7 ], padded stride
    {
        const int d  = t >> 3;   // 0..63
        const int mg = t & 7;    // 0..7
        union { u16 h[8]; short8 s; } u;
#pragma unroll
        for (int i = 0; i < 8; ++i) u.h[i] = Vt[mg * 8 + i][d];
        u16* dst = vTws + ((long)(b * 64 + d)) * VSTRIDE + (m0 & (SEQ - 1)) + mg * 8;
        *reinterpret_cast<short8*>(dst) = u.s;
    }
}

// ---------------- Flash attention: software-pipelined K-loop ----------------
// 32 q-rows per wave (two 16-row MFMA tiles sharing the K/V registers):
// halves L2/L3 K+V traffic per q-row and doubles MFMA per load.
// Iteration i runs PV(i) interleaved with S-phase(i+1); K prefetched 2 tiles
// ahead, V issued at iteration top. Fixed-shift exp2 softmax.
// XCD-batch affinity: blockIdx%8 = XCD (round-robin); batch b is mapped to
// XCDs {2b,2b+1} so each XCD's L2 only holds one batch's K+V (~1.6 MB < 4 MB).
__global__ __launch_bounds__(256, 3) void attn_kernel(
    const u32* __restrict__ xs,
    const u16* __restrict__ qw, const u16* __restrict__ kw,
    const u16* __restrict__ vTw, const u32* __restrict__ maskbits,
    char* __restrict__ part, void* __restrict__ out)
{
    __shared__ __align__(16) char smraw[36864];  // Ps[4][2][2][16][72] u16 / Ow[4][32][64] f32
    __shared__ float lwS[4][32];
    u16   (*Ps)[2][2][16][72] = reinterpret_cast<u16(*)[2][2][16][72]>(smraw);
    float (*Ow)[32][64]       = reinterpret_cast<float(*)[32][64]>(smraw);

    const int flag = sniff_bf16(xs);
    const int t  = threadIdx.x;
    const int l  = t & 63;
    const int w  = t >> 6;
    const int li = l & 15;
    const int g  = l >> 4;
    const int g4 = g * 4;

    // XCD-affine decode: b = (bid%8)>>1; s = per-batch slot, big tiles first.
    const int bid = blockIdx.x;          // grid = 768
    const int b   = (bid & 7) >> 1;
    const int s   = (bid >> 3) * 2 + (bid & 1);   // 0..191
    int qt32, c;
    if (s < 128) { qt32 = 127 - (s >> 1); c = s & 1; }  // split-K tiles (nkt>32)
    else         { qt32 = 191 - s;        c = 0;     }  // single-chunk tiles
    const int q0    = qt32 * 32;
    const int nkt   = (qt32 >> 1) + 1;
    const int ktBeg = c * 32;
    const int ktEnd = min(ktBeg + 32, nkt);
    const int nc    = (qt32 >= 64) ? 2 : 1;

    const u16* qrow = qw + ((long)(b * SEQ + q0 + li)) * HD + g * 8;
    short8 qf0 = *reinterpret_cast<const short8*>(qrow);
    short8 qf1 = *reinterpret_cast<const short8*>(qrow + 32);
    short8 qf2 = *reinterpret_cast<const short8*>(qrow + 16 * HD);
    short8 qf3 = *reinterpret_cast<const short8*>(qrow + 16 * HD + 32);

    short8 ones;
#pragma unroll
    for (int i = 0; i < 8; ++i) ones[i] = (short)0x3F80;  // bf16 1.0

    f32x4 O[8];
#pragma unroll
    for (int i = 0; i < 8; ++i) O[i] = (f32x4){0.f, 0.f, 0.f, 0.f};
    f32x4 l4A = (f32x4){0.f, 0.f, 0.f, 0.f};
    f32x4 l4B = (f32x4){0.f, 0.f, 0.f, 0.f};
    const int qgA = q0 + li;
    const int qgB = q0 + 16 + li;
    const f32x4 z4 = (f32x4){0.f, 0.f, 0.f, 0.f};

    const u16* kbase = kw  + ((long)(b * SEQ) + li) * HD + g * 8;
    const u16* vbase = vTw + ((long)(b * 64)  + li) * VSTRIDE + g * 8;

    const int kt0 = ktBeg + w;
    const int ntile = (kt0 < ktEnd) ? (((ktEnd - kt0) + 3) >> 2) : 0;
    const int toffLast = (ntile - 1) * 4;

    short8 ka[8];
    auto kload = [&](int toff) {                  // clamped prefetch
        const int tt = (toff > toffLast) ? toffLast : toff;
        const u16* kp = kbase + (long)((kt0 + tt) * 64) * HD;
#pragma unroll
        for (int sub = 0; sub < 4; ++sub) {
            ka[2*sub]   = *reinterpret_cast<const short8*>(kp + sub * 16 * HD);
            ka[2*sub+1] = *reinterpret_cast<const short8*>(kp + sub * 16 * HD + 32);
        }
    };
    auto sphase = [&](int toff, int pb) {         // S^T + softmax -> Ps[w][pb][tile]
        const int k0 = (kt0 + toff) * 64;
        const u32 mb0 = maskbits[b * 128 + (k0 >> 5)];
        const u32 mb1 = maskbits[b * 128 + (k0 >> 5) + 1];
#pragma unroll
        for (int sub = 0; sub < 4; ++sub) {
            f32x4 aA = __builtin_amdgcn_mfma_f32_16x16x32_bf16(ka[2*sub],   qf0, z4, 0, 0, 0);
            aA       = __builtin_amdgcn_mfma_f32_16x16x32_bf16(ka[2*sub+1], qf1, aA, 0, 0, 0);
            f32x4 aB = __builtin_amdgcn_mfma_f32_16x16x32_bf16(ka[2*sub],   qf2, z4, 0, 0, 0);
            aB       = __builtin_amdgcn_mfma_f32_16x16x32_bf16(ka[2*sub+1], qf3, aB, 0, 0, 0);
            const u32 word = (sub & 2) ? mb1 : mb0;
            float pA[4], pB[4];
#pragma unroll
            for (int r = 0; r < 4; ++r) {
                const int kloc = sub * 16 + g4 + r;
                const bool bit = ((word >> ((sub & 1) * 16 + g4 + r)) & 1u) != 0u;
                const bool keepA = ((k0 + kloc) <= qgA) && bit;
                const bool keepB = ((k0 + kloc) <= qgB) && bit;
                pA[r] = ex2(fmaf(aA[r], SSCALE, keepA ? CSHIFT : NEGBIG));
                pB[r] = ex2(fmaf(aB[r], SSCALE, keepB ? CSHIFT : NEGBIG));
            }
            *reinterpret_cast<uint2*>(&Ps[w][pb][0][li][sub * 16 + g4]) =
                make_uint2(pkbf(pA[0], pA[1]), pkbf(pA[2], pA[3]));
            *reinterpret_cast<uint2*>(&Ps[w][pb][1][li][sub * 16 + g4]) =
                make_uint2(pkbf(pB[0], pB[1]), pkbf(pB[2], pB[3]));
        }
    };

    if (ntile > 0) {
        kload(0);
        sphase(0, 0);
        kload(4);
    }
    for (int i = 0; i < ntile; ++i) {
        const int k0 = (kt0 + 4 * i) * 64;
        short8 vf[8];
#pragma unroll
        for (int ds = 0; ds < 4; ++ds) {
            const u16* vr = vbase + (long)(ds * 16) * VSTRIDE + k0;
            vf[2*ds]   = *reinterpret_cast<const short8*>(vr);
            vf[2*ds+1] = *reinterpret_cast<const short8*>(vr + 32);
        }
        const int bufA = i & 1;
        short8 A1A = *reinterpret_cast<const short8*>(&Ps[w][bufA][0][li][g * 8]);
        short8 A2A = *reinterpret_cast<const short8*>(&Ps[w][bufA][0][li][32 + g * 8]);
        short8 A1B = *reinterpret_cast<const short8*>(&Ps[w][bufA][1][li][g * 8]);
        short8 A2B = *reinterpret_cast<const short8*>(&Ps[w][bufA][1][li][32 + g * 8]);
        if (i + 1 < ntile) {
            sphase(4 * (i + 1), bufA ^ 1);        // overlaps PV(i) below
            kload(4 * (i + 2));
        }
        f32x4 ltA = __builtin_amdgcn_mfma_f32_16x16x32_bf16(A1A, ones, z4,  0, 0, 0);
        ltA       = __builtin_amdgcn_mfma_f32_16x16x32_bf16(A2A, ones, ltA, 0, 0, 0);
        f32x4 ltB = __builtin_amdgcn_mfma_f32_16x16x32_bf16(A1B, ones, z4,  0, 0, 0);
        ltB       = __builtin_amdgcn_mfma_f32_16x16x32_bf16(A2B, ones, ltB, 0, 0, 0);
#pragma unroll
        for (int r = 0; r < 4; ++r) { l4A[r] += ltA[r]; l4B[r] += ltB[r]; }
#pragma unroll
        for (int ds = 0; ds < 4; ++ds) {
            O[ds]     = __builtin_amdgcn_mfma_f32_16x16x32_bf16(A1A, vf[2*ds],   O[ds],     0, 0, 0);
            O[ds]     = __builtin_amdgcn_mfma_f32_16x16x32_bf16(A2A, vf[2*ds+1], O[ds],     0, 0, 0);
            O[4 + ds] = __builtin_amdgcn_mfma_f32_16x16x32_bf16(A1B, vf[2*ds],   O[4 + ds], 0, 0, 0);
            O[4 + ds] = __builtin_amdgcn_mfma_f32_16x16x32_bf16(A2B, vf[2*ds+1], O[4 + ds], 0, 0, 0);
        }
    }

    __syncthreads();   // all Ps reads done before Ow overlay writes
#pragma unroll
    for (int tile = 0; tile < 2; ++tile)
#pragma unroll
        for (int ds = 0; ds < 4; ++ds)
#pragma unroll
            for (int r = 0; r < 4; ++r)
                Ow[w][tile * 16 + g4 + r][ds * 16 + li] = O[tile * 4 + ds][r];
    if (li == 0) {
#pragma unroll
        for (int r = 0; r < 4; ++r) {
            lwS[w][g4 + r]      = l4A[r];
            lwS[w][16 + g4 + r] = l4B[r];
        }
    }
    __syncthreads();

    // combine 4 wave partials; thread -> (q = t>>3, d = (t&7)*8 .. +7)
    {
        const int qq = t >> 3;          // 0..31
        const int dd = (t & 7) * 8;     // 0..56
        float L = lwS[0][qq] + lwS[1][qq] + lwS[2][qq] + lwS[3][qq];
        float a8[8];
#pragma unroll
        for (int j = 0; j < 8; ++j) a8[j] = 0.f;
#pragma unroll
        for (int wv = 0; wv < 4; ++wv) {
            float4 o0 = *reinterpret_cast<const float4*>(&Ow[wv][qq][dd]);
            float4 o1 = *reinterpret_cast<const float4*>(&Ow[wv][qq][dd + 4]);
            a8[0] += o0.x; a8[1] += o0.y; a8[2] += o0.z; a8[3] += o0.w;
            a8[4] += o1.x; a8[5] += o1.y; a8[6] += o1.z; a8[7] += o1.w;
        }
        if (nc == 1) {
            const float rl = (L > 0.f) ? 1.f / L : 0.f;
#pragma unroll
            for (int j = 0; j < 8; ++j) a8[j] *= rl;
            const long row = (long)(b * SEQ + q0 + qq);
            if (flag) {
                uint4 st = make_uint4(pkbf(a8[0], a8[1]), pkbf(a8[2], a8[3]),
                                      pkbf(a8[4], a8[5]), pkbf(a8[6], a8[7]));
                *reinterpret_cast<uint4*>((u16*)out + row * HD + dd) = st;
            } else {
                *reinterpret_cast<float4*>((float*)out + row * HD + dd) =
                    make_float4(a8[0], a8[1], a8[2], a8[3]);
                *reinterpret_cast<float4*>((float*)out + row * HD + dd + 4) =
                    make_float4(a8[4], a8[5], a8[6], a8[7]);
            }
        } else {
            char* slot = part + ((long)((b * 64 + (qt32 - 64)) * 2 + c)) * PSLOTB;
            uint4 st = make_uint4(pkbf(a8[0], a8[1]), pkbf(a8[2], a8[3]),
                                  pkbf(a8[4], a8[5]), pkbf(a8[6], a8[7]));
            *reinterpret_cast<uint4*>((u16*)slot + qq * 64 + dd) = st;
            if ((t & 7) == 0)
                *reinterpret_cast<float*>(slot + 4096 + qq * 4) = L;
        }
    }
}

// ---------------- merge split-K partials (qt32 >= 64): plain sum ----------
__global__ __launch_bounds__(256) void merge_kernel(
    const u32* __restrict__ xs, const char* __restrict__ part,
    void* __restrict__ out)
{
    const int flag = sniff_bf16(xs);
    const int bid = blockIdx.x;         // 256
    const int b    = bid & 3;
    const int qt32 = 64 + (bid >> 2);
    const int t  = threadIdx.x;
    const int qq = t >> 3;              // 0..31
    const int dd = (t & 7) * 8;         // 0..56
    const char* s0 = part + ((long)((b * 64 + (qt32 - 64)) * 2)) * PSLOTB;
    const char* s1 = s0 + PSLOTB;
    float l0 = *reinterpret_cast<const float*>(s0 + 4096 + qq * 4);
    float l1 = *reinterpret_cast<const float*>(s1 + 4096 + qq * 4);
    float L  = l0 + l1;
    float rl = (L > 0.f) ? 1.f / L : 0.f;
    ushort4 a0 = *reinterpret_cast<const ushort4*>((const u16*)s0 + qq * 64 + dd);
    ushort4 a1 = *reinterpret_cast<const ushort4*>((const u16*)s0 + qq * 64 + dd + 4);
    ushort4 b0 = *reinterpret_cast<const ushort4*>((const u16*)s1 + qq * 64 + dd);
    ushort4 b1 = *reinterpret_cast<const ushort4*>((const u16*)s1 + qq * 64 + dd + 4);
    float r0 = (bfbits2f(a0.x) + bfbits2f(b0.x)) * rl;
    float r1 = (bfbits2f(a0.y) + bfbits2f(b0.y)) * rl;
    float r2 = (bfbits2f(a0.z) + bfbits2f(b0.z)) * rl;
    float r3 = (bfbits2f(a0.w) + bfbits2f(b0.w)) * rl;
    float r4 = (bfbits2f(a1.x) + bfbits2f(b1.x)) * rl;
    float r5 = (bfbits2f(a1.y) + bfbits2f(b1.y)) * rl;
    float r6 = (bfbits2f(a1.z) + bfbits2f(b1.z)) * rl;
    float r7 = (bfbits2f(a1.w) + bfbits2f(b1.w)) * rl;
    const long row = (long)(b * SEQ + qt32 * 32 + qq);
    if (flag) {
        uint4 st = make_uint4(pkbf(r0, r1), pkbf(r2, r3),
                              pkbf(r4, r5), pkbf(r6, r7));
        *reinterpret_cast<uint4*>((u16*)out + row * HD + dd) = st;
    } else {
        *reinterpret_cast<float4*>((float*)out + row * HD + dd) =
            make_float4(r0, r1, r2, r3);
        *reinterpret_cast<float4*>((float*)out + row * HD + dd + 4) =
            make_float4(r4, r5, r6, r7);
    }
}

extern "C" void kernel_launch(void* const* d_in, const int* in_sizes, int n_in,
                              void* d_out, int out_size, void* d_ws, size_t ws_size,
                              hipStream_t stream) {
    const void* x   = d_in[0];
    const int* mask = (const int*)d_in[1];
    const void* wq  = d_in[2];
    const void* wk  = d_in[3];
    const void* wv  = d_in[4];
    const u32* xs   = (const u32*)x;

    u16* q    = (u16*)d_ws;                          // 2 MB
    u16* k    = q  + (long)NROW * HD;                // 2 MB
    u16* vT   = k  + (long)NROW * HD;                // 2.16 MB
    u32* mb   = (u32*)(vT + (long)BATCH * 64 * VSTRIDE);  // 2 KB
    char* part = (char*)(mb + 512);                  // 2.16 MB

    qkv_kernel  <<<258, 512, 0, stream>>>(x, wq, wk, wv, mask, q, k, vT, mb);
    attn_kernel <<<768, 256, 0, stream>>>(xs, q, k, vT, mb, part, d_out);
    merge_kernel<<<256, 256, 0, stream>>>(xs, part, d_out);
}